// Round 2
// baseline (5970.406 us; speedup 1.0000x reference)
//
#include <hip/hip_runtime.h>
#include <cstdint>
#include <cstddef>

typedef unsigned short u16;

#define HW4   1792      // 28*64
#define FCH   631       // final feat channels
#define OUTOFF ((size_t)57344)   // feat region element offset in d_out

__device__ __forceinline__ float b2f(u16 u){
  union { unsigned int i; float f; } v; v.i = ((unsigned int)u) << 16; return v.f;
}
__device__ __forceinline__ u16 f2b(float f){
  unsigned int x = __float_as_uint(f);
  return (u16)((x + 0x7fffu + ((x >> 16) & 1u)) >> 16);
}
__device__ __forceinline__ float lrelu(float v){ return v >= 0.f ? v : 0.1f * v; }
// dtype probe: cam_intri[0]=500.0. bf16 pair read as float -> 2.4e-41 ; fp32 -> 500.0
__device__ __forceinline__ bool is_f32(const void* probe){ return ((const float*)probe)[0] > 1.0f; }
__device__ __forceinline__ float ldg_(const void* p, size_t i, bool f){
  return f ? ((const float*)p)[i] : b2f(((const u16*)p)[i]);
}
__device__ __forceinline__ void stg_(void* p, size_t i, float v, bool f){
  if (f) ((float*)p)[i] = v; else ((u16*)p)[i] = f2b(v);
}

// ---------------------------------------------------------------- M = K R(q) Kinv
__global__ void k_M(const void* __restrict__ quat, const void* __restrict__ K,
                    const void* __restrict__ Kinv, float* __restrict__ Mout){
  bool f = is_f32(K);
  int b = threadIdx.x;
  if (b >= 16) return;
  float q0 = ldg_(quat,b*4+0,f), q1 = ldg_(quat,b*4+1,f);
  float q2 = ldg_(quat,b*4+2,f), q3 = ldg_(quat,b*4+3,f);
  float n = sqrtf(q0*q0 + q1*q1 + q2*q2 + q3*q3);
  float w = q0/n, x = q1/n, y = q2/n, z = q3/n;
  float R[9];
  R[0] = 1.f - 2.f*(y*y + z*z); R[1] = 2.f*(x*y - w*z); R[2] = 2.f*(x*z + w*y);
  R[3] = 2.f*(x*y + w*z); R[4] = 1.f - 2.f*(x*x + z*z); R[5] = 2.f*(y*z - w*x);
  R[6] = 2.f*(x*z - w*y); R[7] = 2.f*(y*z + w*x); R[8] = 1.f - 2.f*(x*x + y*y);
  float Kf[9], Ki[9];
  for (int i = 0; i < 9; i++){ Kf[i] = ldg_(K,i,f); Ki[i] = ldg_(Kinv,i,f); }
  float T[9];
  for (int r = 0; r < 3; r++)
    for (int c = 0; c < 3; c++)
      T[r*3+c] = R[r*3+0]*Ki[0*3+c] + R[r*3+1]*Ki[1*3+c] + R[r*3+2]*Ki[2*3+c];
  for (int r = 0; r < 3; r++)
    for (int c = 0; c < 3; c++)
      Mout[b*9 + r*3 + c] = Kf[r*3+0]*T[0*3+c] + Kf[r*3+1]*T[1*3+c] + Kf[r*3+2]*T[2*3+c];
}

// ---------------------------------------- rotation-flow, column (W 1024->64) pass
// tmpA layout: [b][c][xo(64)][yf(448)]
__global__ void k_rflow_col(const float* __restrict__ Mws, float* __restrict__ tmpA){
  int t = blockIdx.x * 256 + threadIdx.x;      // 16*448*64 = 458752 exactly
  int xo = t & 63;
  int yf = (t >> 6) % 448;
  int b  = t / (448*64);
  const float* M = Mws + b*9;
  float m0=M[0],m1=M[1],m2=M[2],m3=M[3],m4=M[4],m5=M[5],m6=M[6],m7=M[7],m8=M[8];
  float cx = 16.f*xo + 7.5f;
  float yff = (float)yf;
  float su = 0.f, sv = 0.f, wsum = 0.f;
  for (int i = 0; i < 32; i++){
    int xi = 16*xo - 8 + i;
    if (xi < 0 || xi > 1023) continue;
    float xf = (float)xi;
    float wgt = 1.f - fabsf(xf - cx) * (1.f/16.f);
    float den = m6*xf + m7*yff + m8;
    float inv = 1.f / den;
    float u = (m0*xf + m1*yff + m2)*inv - xf;
    float v = (m3*xf + m4*yff + m5)*inv - yff;
    su += wgt*u; sv += wgt*v; wsum += wgt;
  }
  float rn = 1.f / wsum;
  tmpA[((size_t)(b*2+0)*64 + xo)*448 + yf] = su*rn;
  tmpA[((size_t)(b*2+1)*64 + xo)*448 + yf] = sv*rn;
}

// ---------------------------------------- rotation-flow, row (448->28) + /SCALE
__global__ void k_rflow_row(const float* __restrict__ tmpA, float* __restrict__ rfr,
                            void* __restrict__ outb, const void* probe){
  bool f = is_f32(probe);
  int t = blockIdx.x * 256 + threadIdx.x;      // 28672 exactly
  int xo = t & 63;
  int yo = (t >> 6) % 28;
  int b  = t / HW4;
  float cy = 16.f*yo + 7.5f;
  for (int c = 0; c < 2; c++){
    const float* col = tmpA + ((size_t)(b*2+c)*64 + xo)*448;
    float s = 0.f, wsum = 0.f;
    for (int i = 0; i < 32; i++){
      int yi = 16*yo - 8 + i;
      if (yi < 0 || yi > 447) continue;
      float wgt = 1.f - fabsf((float)yi - cy) * (1.f/16.f);
      s += wgt * col[yi]; wsum += wgt;
    }
    float val = s / (wsum * 16.0f);   // includes /SCALE
    rfr[(size_t)(b*2+c)*HW4 + yo*64 + xo] = val;
    stg_(outb, OUTOFF + ((size_t)b*FCH + 529 + c)*HW4 + yo*64 + xo, val, f);
  }
}

// ---------------------------------------------------- deconv4s2 of prev_flow (2ch)
__global__ void k_dflow(const void* __restrict__ pf, const void* __restrict__ w,
                        const void* __restrict__ bias, float* __restrict__ tflow,
                        void* __restrict__ outb, const void* probe){
  bool f = is_f32(probe);
  int t = blockIdx.x * 256 + threadIdx.x;      // 57344 exactly
  int x = t & 63;
  int y = (t >> 6) % 28;
  int co = (t / HW4) & 1;
  int b  = t / (2*HW4);
  float acc = ldg_(bias, co, f);
  for (int ky = 0; ky < 4; ky++){
    int dy = y + ky - 2;
    if (dy < 0 || dy > 26 || (dy & 1)) continue;
    int iy = dy >> 1;
    for (int kx = 0; kx < 4; kx++){
      int dx = x + kx - 2;
      if (dx < 0 || dx > 62 || (dx & 1)) continue;
      int ix = dx >> 1;
      for (int ci = 0; ci < 2; ci++){
        acc += ldg_(pf, ((size_t)(b*2+ci)*14 + iy)*32 + ix, f) *
               ldg_(w,  (size_t)ci*32 + co*16 + (3-ky)*4 + (3-kx), f);
      }
    }
  }
  tflow[(size_t)(b*2+co)*HW4 + y*64 + x] = acc;
  stg_(outb, OUTOFF + ((size_t)b*FCH + 627 + co)*HW4 + y*64 + x, acc, f);
}

// ---------------------------------------------------- deconv4s2 of prev_feat (663->2)
__global__ void k_dfeat(const void* __restrict__ pfeat, const void* __restrict__ w,
                        const void* __restrict__ bias, void* __restrict__ outb,
                        const void* probe){
  bool f = is_f32(probe);
  int t = blockIdx.x * 256 + threadIdx.x;      // 57344 exactly
  int x = t & 63;
  int y = (t >> 6) % 28;
  int co = (t / HW4) & 1;
  int b  = t / (2*HW4);
  float acc = ldg_(bias, co, f);
  if (f){
    const float* pin = (const float*)pfeat + (size_t)b*663*448;
    const float* wf  = (const float*)w;
    for (int ky = 0; ky < 4; ky++){
      int dy = y + ky - 2;
      if (dy < 0 || dy > 26 || (dy & 1)) continue;
      int iy = dy >> 1;
      for (int kx = 0; kx < 4; kx++){
        int dx = x + kx - 2;
        if (dx < 0 || dx > 62 || (dx & 1)) continue;
        int ix = dx >> 1;
        const float* ip = pin + iy*32 + ix;
        const float* wp = wf + co*16 + (3-ky)*4 + (3-kx);
        #pragma unroll 4
        for (int ci = 0; ci < 663; ci++) acc += ip[ci*448] * wp[ci*32];
      }
    }
  } else {
    const u16* pin = (const u16*)pfeat + (size_t)b*663*448;
    const u16* wf  = (const u16*)w;
    for (int ky = 0; ky < 4; ky++){
      int dy = y + ky - 2;
      if (dy < 0 || dy > 26 || (dy & 1)) continue;
      int iy = dy >> 1;
      for (int kx = 0; kx < 4; kx++){
        int dx = x + kx - 2;
        if (dx < 0 || dx > 62 || (dx & 1)) continue;
        int ix = dx >> 1;
        const u16* ip = pin + iy*32 + ix;
        const u16* wp = wf + co*16 + (3-ky)*4 + (3-kx);
        #pragma unroll 4
        for (int ci = 0; ci < 663; ci++) acc += b2f(ip[ci*448]) * b2f(wp[ci*32]);
      }
    }
  }
  stg_(outb, OUTOFF + ((size_t)b*FCH + 629 + co)*HW4 + y*64 + x, acc, f);
}

// ---------------------------------------------------------------- copy tenOne into feat
__global__ void k_copy_one(const void* __restrict__ one, void* __restrict__ outb,
                           const void* probe){
  bool f = is_f32(probe);
  int t = blockIdx.x * 256 + threadIdx.x;      // 2752512 exactly
  int p = t % HW4;
  int c = (t / HW4) % 96;
  int b = t / (96*HW4);
  stg_(outb, OUTOFF + ((size_t)b*FCH + 531 + c)*HW4 + p,
       ldg_(one, (size_t)(b*96+c)*HW4 + p, f), f);
}

// ------------------------------------------- fused double-warp of tenTwo (16-pt gather)
__global__ void k_warp2(const void* __restrict__ two, const float* __restrict__ rfr,
                        const float* __restrict__ tflow, float* __restrict__ wrp2,
                        const void* probe){
  bool f = is_f32(probe);
  int t = blockIdx.x * 256 + threadIdx.x;      // 2752512 exactly
  int x = t & 63;
  int y = (t >> 6) % 28;
  int c = (t / HW4) % 96;
  int b = t / (96*HW4);
  float qu = tflow[(size_t)(b*2+0)*HW4 + y*64 + x] * 1.25f;
  float qv = tflow[(size_t)(b*2+1)*HW4 + y*64 + x] * 1.25f;
  float qx = (float)x + qu, qy = (float)y + qv;
  float qx0 = floorf(qx), qy0 = floorf(qy);
  float wx = qx - qx0, wy = qy - qy0;
  const size_t cb = (size_t)(b*96+c)*HW4;
  float acc = 0.f;
  #pragma unroll
  for (int a = 0; a < 2; a++){
    #pragma unroll
    for (int bb = 0; bb < 2; bb++){
      float ry = qy0 + (float)a, rx = qx0 + (float)bb;
      if (ry < 0.f || ry > 27.f || rx < 0.f || rx > 63.f) continue;
      float W = (a ? wy : 1.f-wy) * (bb ? wx : 1.f-wx);
      int iry = (int)ry, irx = (int)rx;
      float su = rfr[(size_t)(b*2+0)*HW4 + iry*64 + irx];
      float sv = rfr[(size_t)(b*2+1)*HW4 + iry*64 + irx];
      float sx = rx + su, sy = ry + sv;
      float sx0 = floorf(sx), sy0 = floorf(sy);
      float swx = sx - sx0, swy = sy - sy0;
      float inner = 0.f;
      #pragma unroll
      for (int aa = 0; aa < 2; aa++){
        #pragma unroll
        for (int cc2 = 0; cc2 < 2; cc2++){
          float gy2 = sy0 + (float)aa, gx2 = sx0 + (float)cc2;
          if (gy2 < 0.f || gy2 > 27.f || gx2 < 0.f || gx2 > 63.f) continue;
          float wv = (aa ? swy : 1.f-swy) * (cc2 ? swx : 1.f-swx);
          inner += wv * ldg_(two, cb + (size_t)((int)gy2*64 + (int)gx2), f);
        }
      }
      acc += W * inner;
    }
  }
  wrp2[t] = acc;
}

// ---------------------------------------------------------------- correlation (81 ch)
__global__ void k_corr(const void* __restrict__ one, const float* __restrict__ two,
                       void* __restrict__ outb, const void* probe){
  bool f = is_f32(probe);
  int t = blockIdx.x * 256 + threadIdx.x;      // 16*9*1792 = 258048 exactly
  int x  = t & 63;
  int y  = (t >> 6) % 28;
  int dy = (t / HW4) % 9;
  int b  = t / (9*HW4);
  float acc[9];
  #pragma unroll
  for (int i = 0; i < 9; i++) acc[i] = 0.f;
  int row = y + dy - 4;
  if (row >= 0 && row < 28){
    for (int c = 0; c < 96; c++){
      float f1 = ldg_(one, (size_t)(b*96+c)*HW4 + y*64 + x, f);
      const float* rp = two + (size_t)(b*96+c)*HW4 + row*64;
      #pragma unroll
      for (int dx = 0; dx < 9; dx++){
        int xx = x + dx - 4;
        if (xx >= 0 && xx < 64) acc[dx] += f1 * rp[xx];
      }
    }
  }
  #pragma unroll
  for (int dx = 0; dx < 9; dx++){
    float v = lrelu(acc[dx] * (1.f/96.f));
    stg_(outb, OUTOFF + ((size_t)b*FCH + 448 + dy*9 + dx)*HW4 + y*64 + x, v, f);
  }
}

// ---------------------------------------------------------------- 3x3 conv + lrelu
// block: 256 threads = 64 x-lanes * 4 groups; each thread -> 8 output channels
// grid: (448 = B*H, ceil(Cout/32)). Input & output both live in d_out (dtype per flag).
__global__ __launch_bounds__(256) void k_conv(
    void* __restrict__ base, size_t in_off,
    const void* __restrict__ w, const void* __restrict__ bias,
    int Cin, int Cout, size_t out_off, size_t out_bstr, const void* probe){
  __shared__ float s_in[32*3*66];    // 25344 B
  __shared__ float s_w[32*9*32];     // 36864 B
  bool f = is_f32(probe);
  int tid = threadIdx.x;
  int x = tid & 63;
  int g = tid >> 6;
  int by = blockIdx.x;
  int b = by / 28, y = by % 28;
  int co_base = blockIdx.y * 32;
  const size_t FB = (size_t)FCH * HW4;
  float acc[8];
  #pragma unroll
  for (int j = 0; j < 8; j++) acc[j] = 0.f;

  for (int ci0 = 0; ci0 < Cin; ci0 += 32){
    int cc = min(32, Cin - ci0);
    if (f){
      const float* inb = (const float*)base + in_off + (size_t)b*FB;
      for (int e = tid; e < cc*198; e += 256){
        int ci = e / 198; int rem = e - ci*198;
        int r = rem / 66; int xx = rem - r*66;
        int iy = y + r - 1; int ix = xx - 1;
        float v = 0.f;
        if (iy >= 0 && iy < 28 && ix >= 0 && ix < 64)
          v = inb[(size_t)(ci0+ci)*HW4 + iy*64 + ix];
        s_in[(ci*3 + r)*66 + xx] = v;
      }
      const float* wf = (const float*)w;
      for (int e = tid; e < cc*288; e += 256){
        int co_i = e & 31; int k = (e >> 5) % 9; int ci = e / 288;
        int co = co_base + co_i;
        float v = 0.f;
        if (co < Cout) v = wf[((size_t)co*Cin + ci0 + ci)*9 + k];
        s_w[(ci*9 + k)*32 + co_i] = v;
      }
    } else {
      const u16* inb = (const u16*)base + in_off + (size_t)b*FB;
      for (int e = tid; e < cc*198; e += 256){
        int ci = e / 198; int rem = e - ci*198;
        int r = rem / 66; int xx = rem - r*66;
        int iy = y + r - 1; int ix = xx - 1;
        float v = 0.f;
        if (iy >= 0 && iy < 28 && ix >= 0 && ix < 64)
          v = b2f(inb[(size_t)(ci0+ci)*HW4 + iy*64 + ix]);
        s_in[(ci*3 + r)*66 + xx] = v;
      }
      const u16* wf = (const u16*)w;
      for (int e = tid; e < cc*288; e += 256){
        int co_i = e & 31; int k = (e >> 5) % 9; int ci = e / 288;
        int co = co_base + co_i;
        float v = 0.f;
        if (co < Cout) v = b2f(wf[((size_t)co*Cin + ci0 + ci)*9 + k]);
        s_w[(ci*9 + k)*32 + co_i] = v;
      }
    }
    __syncthreads();
    for (int ci = 0; ci < cc; ci++){
      const float* si = &s_in[ci*198 + x];
      const float* sw = &s_w[ci*288 + 8*g];
      #pragma unroll
      for (int ky = 0; ky < 3; ky++){
        #pragma unroll
        for (int kx = 0; kx < 3; kx++){
          float v = si[ky*66 + kx];
          const float* wp = sw + (ky*3 + kx)*32;
          float4 wa = *(const float4*)(wp);
          float4 wb = *(const float4*)(wp + 4);
          acc[0] += wa.x*v; acc[1] += wa.y*v; acc[2] += wa.z*v; acc[3] += wa.w*v;
          acc[4] += wb.x*v; acc[5] += wb.y*v; acc[6] += wb.z*v; acc[7] += wb.w*v;
        }
      }
    }
    __syncthreads();
  }
  #pragma unroll
  for (int j = 0; j < 8; j++){
    int co = co_base + 8*g + j;
    if (co < Cout){
      float v = lrelu(acc[j] + ldg_(bias, co, f));
      stg_(base, out_off + (size_t)b*out_bstr + (size_t)co*HW4 + y*64 + x, v, f);
    }
  }
}

// ----------------------------------------------------------------------------------
extern "C" void kernel_launch(void* const* d_in, const int* in_sizes, int n_in,
                              void* d_out, int out_size, void* d_ws, size_t ws_size,
                              hipStream_t stream){
  const void* tenOne    = d_in[0];
  const void* tenTwo    = d_in[1];
  const void* prev_flow = d_in[2];
  const void* prev_feat = d_in[3];
  const void* quat      = d_in[4];
  const void* K         = d_in[5];
  const void* Kinv      = d_in[6];
  const void* upflow_w  = d_in[7];
  const void* upflow_b  = d_in[8];
  const void* upfeat_w  = d_in[9];
  const void* upfeat_b  = d_in[10];
  const void* w1 = d_in[11];  const void* b1 = d_in[12];
  const void* w2 = d_in[13];  const void* b2 = d_in[14];
  const void* w3 = d_in[15];  const void* b3 = d_in[16];
  const void* w4 = d_in[17];  const void* b4 = d_in[18];
  const void* w5 = d_in[19];  const void* b5 = d_in[20];
  const void* w6 = d_in[21];  const void* b6 = d_in[22];
  const void* probe = K;    // cam_intri[0]==500.0 discriminates dtype

  float* ws    = (float*)d_ws;
  float* Mws   = ws;                         // 160
  float* tmpA  = ws + 160;                   // 917504
  float* rfr   = ws + 917664;                // 57344
  float* tflow = ws + 975008;                // 57344
  float* wrp2  = ws + 1032352;               // 2752512 (end 3784864 floats ~15.1MB)

  k_M<<<1, 64, 0, stream>>>(quat, K, Kinv, Mws);
  k_rflow_col<<<1792, 256, 0, stream>>>(Mws, tmpA);
  k_rflow_row<<<112, 256, 0, stream>>>(tmpA, rfr, d_out, probe);
  k_dflow<<<224, 256, 0, stream>>>(prev_flow, upflow_w, upflow_b, tflow, d_out, probe);
  k_dfeat<<<224, 256, 0, stream>>>(prev_feat, upfeat_w, upfeat_b, d_out, probe);
  k_copy_one<<<10752, 256, 0, stream>>>(tenOne, d_out, probe);
  k_warp2<<<10752, 256, 0, stream>>>(tenTwo, rfr, tflow, wrp2, probe);
  k_corr<<<1008, 256, 0, stream>>>(tenOne, wrp2, d_out, probe);

  const size_t FB = (size_t)FCH * HW4;
  const size_t f0 = OUTOFF;
  k_conv<<<dim3(448,4), 256, 0, stream>>>(d_out, f0 + (size_t)448*HW4, w1, b1, 183, 128,
                                          f0 + (size_t)320*HW4, FB, probe);
  k_conv<<<dim3(448,4), 256, 0, stream>>>(d_out, f0 + (size_t)320*HW4, w2, b2, 311, 128,
                                          f0 + (size_t)192*HW4, FB, probe);
  k_conv<<<dim3(448,3), 256, 0, stream>>>(d_out, f0 + (size_t)192*HW4, w3, b3, 439, 96,
                                          f0 + (size_t)96*HW4, FB, probe);
  k_conv<<<dim3(448,2), 256, 0, stream>>>(d_out, f0 + (size_t)96*HW4, w4, b4, 535, 64,
                                          f0 + (size_t)32*HW4, FB, probe);
  k_conv<<<dim3(448,1), 256, 0, stream>>>(d_out, f0 + (size_t)32*HW4, w5, b5, 599, 32,
                                          f0, FB, probe);
  k_conv<<<dim3(448,1), 256, 0, stream>>>(d_out, f0, w6, b6, 631, 2,
                                          0, (size_t)2*HW4, probe);
}